// Round 1
// baseline (1615.362 us; speedup 1.0000x reference)
//
#include <hip/hip_runtime.h>
#include <math.h>

#define TB 256
#define NB 32
#define NC 128
#define NHW 3136
#define ND 64
#define NT 49

__device__ __forceinline__ float wsum64(float v){
    v += __shfl_xor(v, 32);
    v += __shfl_xor(v, 16);
    v += __shfl_xor(v, 8);
    v += __shfl_xor(v, 4);
    v += __shfl_xor(v, 2);
    v += __shfl_xor(v, 1);
    return v;
}
__device__ __forceinline__ float wsum16(float v){
    v += __shfl_xor(v, 8);
    v += __shfl_xor(v, 4);
    v += __shfl_xor(v, 2);
    v += __shfl_xor(v, 1);
    return v;
}
__device__ __forceinline__ float wmax16(float v){
    v = fmaxf(v, __shfl_xor(v, 8));
    v = fmaxf(v, __shfl_xor(v, 4));
    v = fmaxf(v, __shfl_xor(v, 2));
    v = fmaxf(v, __shfl_xor(v, 1));
    return v;
}

// ---------------- Kernel 1: embed + LN1 + LN2 + QKV ----------------
// grid (49, 32), 256 threads. Outputs q (pre-scaled by 0.125), k, v: [B][N][64]
__global__ __launch_bounds__(TB) void k_embed_qkv(
    const float* __restrict__ x,    // [B][C][HW]
    const float* __restrict__ We,   // [C][D]
    const float* __restrict__ be,
    const float* __restrict__ g1, const float* __restrict__ b1,
    const float* __restrict__ g2, const float* __restrict__ b2,
    const float* __restrict__ Wqkv, // [D][3D]
    const float* __restrict__ bqkv,
    float* __restrict__ qb, float* __restrict__ kb, float* __restrict__ vb)
{
    __shared__ float ts[64 * 68];   // t[j][d], stride 68
    __shared__ float zt[64 * 68];   // z^T[c][j], stride 68

    const int b   = blockIdx.y;
    const int n0  = blockIdx.x * 64;
    const int tid = threadIdx.x;
    const int j0  = (tid >> 4) * 4;     // 4 token rows
    const int d0  = (tid & 15) * 4;     // 4 feature cols

    // ---- Phase A: t[j][d] = sum_c x[b][c][n0+j] * We[c][d] + be[d]
    float acc[4][4];
    #pragma unroll
    for (int i = 0; i < 4; ++i)
        #pragma unroll
        for (int k = 0; k < 4; ++k) acc[i][k] = 0.f;

    const float* xp = x + (size_t)b * NC * NHW + n0 + j0;
    #pragma unroll 4
    for (int c = 0; c < NC; ++c) {
        float4 a = *(const float4*)(xp + (size_t)c * NHW);
        float4 w = *(const float4*)(We + c * ND + d0);
        float av[4] = {a.x, a.y, a.z, a.w};
        float wv[4] = {w.x, w.y, w.z, w.w};
        #pragma unroll
        for (int i = 0; i < 4; ++i)
            #pragma unroll
            for (int k = 0; k < 4; ++k) acc[i][k] = fmaf(av[i], wv[k], acc[i][k]);
    }
    {
        float4 bev = *(const float4*)(be + d0);
        float bv[4] = {bev.x, bev.y, bev.z, bev.w};
        #pragma unroll
        for (int i = 0; i < 4; ++i) {
            float4 r;
            r.x = acc[i][0] + bv[0]; r.y = acc[i][1] + bv[1];
            r.z = acc[i][2] + bv[2]; r.w = acc[i][3] + bv[3];
            *(float4*)&ts[(j0 + i) * 68 + d0] = r;
        }
    }
    __syncthreads();

    // ---- Phase B: double LayerNorm per token row; write transposed z^T[c][j]
    {
        const int lane = tid & 63;
        const int wv_  = tid >> 6;
        const float g1v = g1[lane], b1v = b1[lane];
        const float g2v = g2[lane], b2v = b2[lane];
        for (int rr = 0; rr < 16; ++rr) {
            const int j = wv_ * 16 + rr;
            float v  = ts[j * 68 + lane];
            float mu = wsum64(v) * (1.f / 64.f);
            float dd = v - mu;
            float var = wsum64(dd * dd) * (1.f / 64.f);
            float y  = dd * rsqrtf(var + 1e-5f) * g1v + b1v;
            float mu2 = wsum64(y) * (1.f / 64.f);
            float d2  = y - mu2;
            float var2 = wsum64(d2 * d2) * (1.f / 64.f);
            float z = d2 * rsqrtf(var2 + 1e-5f) * g2v + b2v;
            zt[lane * 68 + j] = z;
        }
    }
    __syncthreads();

    // ---- Phase C: qkv[j][d3] = z[j][:] @ Wqkv + bqkv
    #pragma unroll 1
    for (int blkd = 0; blkd < 3; ++blkd) {
        float a2[4][4];
        #pragma unroll
        for (int i = 0; i < 4; ++i)
            #pragma unroll
            for (int k = 0; k < 4; ++k) a2[i][k] = 0.f;
        #pragma unroll 4
        for (int c = 0; c < ND; ++c) {
            float4 a = *(const float4*)&zt[c * 68 + j0];
            float4 w = *(const float4*)(Wqkv + c * 192 + blkd * 64 + d0);
            float av[4] = {a.x, a.y, a.z, a.w};
            float wv[4] = {w.x, w.y, w.z, w.w};
            #pragma unroll
            for (int i = 0; i < 4; ++i)
                #pragma unroll
                for (int k = 0; k < 4; ++k) a2[i][k] = fmaf(av[i], wv[k], a2[i][k]);
        }
        float4 bq = *(const float4*)(bqkv + blkd * 64 + d0);
        float bv[4] = {bq.x, bq.y, bq.z, bq.w};
        const float scale = (blkd == 0) ? 0.125f : 1.0f;
        float* ob = (blkd == 0) ? qb : (blkd == 1) ? kb : vb;
        #pragma unroll
        for (int i = 0; i < 4; ++i) {
            float4 r;
            r.x = (a2[i][0] + bv[0]) * scale;
            r.y = (a2[i][1] + bv[1]) * scale;
            r.z = (a2[i][2] + bv[2]) * scale;
            r.w = (a2[i][3] + bv[3]) * scale;
            *(float4*)(ob + ((size_t)(b * NHW + n0 + j0 + i)) * ND + d0) = r;
        }
    }
}

// ---------------- Kernel 2: flash attention (fp32) ----------------
// grid (49, 32), 256 threads. ob == qb (in-place overwrite of own tile).
__global__ __launch_bounds__(TB) void k_attn(
    const float* __restrict__ qb, const float* __restrict__ kb,
    const float* __restrict__ vb, float* __restrict__ ob)
{
    __shared__ float Qst[64 * 68];  // Q^T[d][r]
    __shared__ float KP[64 * 68];   // K^T[d][j], then P^T[j][r]
    __shared__ float Vs[64 * 68];   // V[j][d]

    const int b   = blockIdx.y;
    const int n0  = blockIdx.x * 64;
    const int tid = threadIdx.x;
    const int r0  = (tid >> 4) * 4;   // 4 query rows
    const int j0  = (tid & 15) * 4;   // 4 key cols (S) / 4 dims (PV)

    // load Q tile transposed
    #pragma unroll
    for (int i = 0; i < 4; ++i) {
        int f4i = tid + 256 * i;
        int r = f4i >> 4, c4 = f4i & 15;
        float4 qv = *(const float4*)(qb + ((size_t)(b * NHW + n0 + r)) * ND + c4 * 4);
        Qst[(c4 * 4 + 0) * 68 + r] = qv.x;
        Qst[(c4 * 4 + 1) * 68 + r] = qv.y;
        Qst[(c4 * 4 + 2) * 68 + r] = qv.z;
        Qst[(c4 * 4 + 3) * 68 + r] = qv.w;
    }

    float o[4][4];
    float m[4], l[4];
    #pragma unroll
    for (int i = 0; i < 4; ++i) {
        m[i] = -1e30f; l[i] = 0.f;
        #pragma unroll
        for (int k = 0; k < 4; ++k) o[i][k] = 0.f;
    }

    for (int kt = 0; kt < NT; ++kt) {
        __syncthreads();  // prior-step KP/Vs readers done (also orders Q load, iter 0)
        const float* kp = kb + ((size_t)(b * NHW + kt * 64)) * ND;
        const float* vp = vb + ((size_t)(b * NHW + kt * 64)) * ND;
        #pragma unroll
        for (int i = 0; i < 4; ++i) {
            int f4i = tid + 256 * i;
            int r = f4i >> 4, c4 = f4i & 15;
            float4 kv = *(const float4*)(kp + r * ND + c4 * 4);
            KP[(c4 * 4 + 0) * 68 + r] = kv.x;
            KP[(c4 * 4 + 1) * 68 + r] = kv.y;
            KP[(c4 * 4 + 2) * 68 + r] = kv.z;
            KP[(c4 * 4 + 3) * 68 + r] = kv.w;
            float4 vv = *(const float4*)(vp + r * ND + c4 * 4);
            *(float4*)&Vs[r * 68 + c4 * 4] = vv;
        }
        __syncthreads();

        // S = Q @ K^T (scale folded into q)
        float s[4][4];
        #pragma unroll
        for (int i = 0; i < 4; ++i)
            #pragma unroll
            for (int k = 0; k < 4; ++k) s[i][k] = 0.f;
        #pragma unroll 8
        for (int d = 0; d < ND; ++d) {
            float4 aa = *(const float4*)&Qst[d * 68 + r0];
            float4 bb = *(const float4*)&KP[d * 68 + j0];
            float av[4] = {aa.x, aa.y, aa.z, aa.w};
            float bv[4] = {bb.x, bb.y, bb.z, bb.w};
            #pragma unroll
            for (int i = 0; i < 4; ++i)
                #pragma unroll
                for (int k = 0; k < 4; ++k) s[i][k] = fmaf(av[i], bv[k], s[i][k]);
        }

        // online softmax update
        float alpha[4];
        #pragma unroll
        for (int i = 0; i < 4; ++i) {
            float rm = fmaxf(fmaxf(s[i][0], s[i][1]), fmaxf(s[i][2], s[i][3]));
            rm = wmax16(rm);
            float mn = fmaxf(m[i], rm);
            alpha[i] = __expf(m[i] - mn);
            #pragma unroll
            for (int k = 0; k < 4; ++k) s[i][k] = __expf(s[i][k] - mn);
            float rs = (s[i][0] + s[i][1]) + (s[i][2] + s[i][3]);
            rs = wsum16(rs);
            l[i] = l[i] * alpha[i] + rs;
            m[i] = mn;
            #pragma unroll
            for (int k = 0; k < 4; ++k) o[i][k] *= alpha[i];
        }
        __syncthreads();  // everyone done reading KP as K^T

        // store P^T into KP
        #pragma unroll
        for (int i = 0; i < 4; ++i)
            #pragma unroll
            for (int k = 0; k < 4; ++k)
                KP[(j0 + k) * 68 + (r0 + i)] = s[i][k];
        __syncthreads();

        // O += P @ V
        #pragma unroll 8
        for (int j = 0; j < 64; ++j) {
            float4 pa = *(const float4*)&KP[j * 68 + r0];
            float4 vv = *(const float4*)&Vs[j * 68 + j0];
            float pv[4] = {pa.x, pa.y, pa.z, pa.w};
            float vvv[4] = {vv.x, vv.y, vv.z, vv.w};
            #pragma unroll
            for (int i = 0; i < 4; ++i)
                #pragma unroll
                for (int k = 0; k < 4; ++k) o[i][k] = fmaf(pv[i], vvv[k], o[i][k]);
        }
    }

    #pragma unroll
    for (int i = 0; i < 4; ++i) {
        float inv = 1.f / l[i];
        float4 r;
        r.x = o[i][0] * inv; r.y = o[i][1] * inv;
        r.z = o[i][2] * inv; r.w = o[i][3] * inv;
        *(float4*)(ob + ((size_t)(b * NHW + n0 + r0 + i)) * ND + j0) = r;
    }
}

// ---------------- Kernel 3: proj + LN + MLP(gelu) + channel-mean ----------------
// grid (49, 32), 256 threads. out[b*N + n]
__global__ __launch_bounds__(TB) void k_post(
    const float* __restrict__ ain,  // attention output [B][N][64]
    const float* __restrict__ Wp, const float* __restrict__ bp,
    const float* __restrict__ gm, const float* __restrict__ bm,
    const float* __restrict__ W1, const float* __restrict__ bm1,
    const float* __restrict__ W2, const float* __restrict__ bm2,
    float* __restrict__ out)
{
    __shared__ float At[64 * 68];   // A^T[c][j], reused as z2^T[c][j]
    __shared__ float Us[64 * 68];   // u[j][d]
    __shared__ float w2b[64];
    __shared__ float bm2b;

    const int b   = blockIdx.y;
    const int n0  = blockIdx.x * 64;
    const int tid = threadIdx.x;
    const int j0  = (tid >> 4) * 4;
    const int d0  = (tid & 15) * 4;

    if (tid < 64) {
        float s = 0.f;
        for (int d = 0; d < 64; ++d) s += W2[tid * 64 + d];
        w2b[tid] = s * (1.f / 64.f);
    }
    if (tid == 64) {
        float s = 0.f;
        for (int d = 0; d < 64; ++d) s += bm2[d];
        bm2b = s * (1.f / 64.f);
    }
    #pragma unroll
    for (int i = 0; i < 4; ++i) {
        int f4i = tid + 256 * i;
        int r = f4i >> 4, c4 = f4i & 15;
        float4 av = *(const float4*)(ain + ((size_t)(b * NHW + n0 + r)) * ND + c4 * 4);
        At[(c4 * 4 + 0) * 68 + r] = av.x;
        At[(c4 * 4 + 1) * 68 + r] = av.y;
        At[(c4 * 4 + 2) * 68 + r] = av.z;
        At[(c4 * 4 + 3) * 68 + r] = av.w;
    }
    __syncthreads();

    // u = A @ Wp + bp
    float acc[4][4];
    #pragma unroll
    for (int i = 0; i < 4; ++i)
        #pragma unroll
        for (int k = 0; k < 4; ++k) acc[i][k] = 0.f;
    #pragma unroll 4
    for (int c = 0; c < ND; ++c) {
        float4 a = *(const float4*)&At[c * 68 + j0];
        float4 w = *(const float4*)(Wp + c * ND + d0);
        float av[4] = {a.x, a.y, a.z, a.w};
        float wv[4] = {w.x, w.y, w.z, w.w};
        #pragma unroll
        for (int i = 0; i < 4; ++i)
            #pragma unroll
            for (int k = 0; k < 4; ++k) acc[i][k] = fmaf(av[i], wv[k], acc[i][k]);
    }
    {
        float4 bpv = *(const float4*)(bp + d0);
        float bv[4] = {bpv.x, bpv.y, bpv.z, bpv.w};
        #pragma unroll
        for (int i = 0; i < 4; ++i) {
            float4 r;
            r.x = acc[i][0] + bv[0]; r.y = acc[i][1] + bv[1];
            r.z = acc[i][2] + bv[2]; r.w = acc[i][3] + bv[3];
            *(float4*)&Us[(j0 + i) * 68 + d0] = r;
        }
    }
    __syncthreads();

    // LN (gm, bm); write z^T into At
    {
        const int lane = tid & 63;
        const int wv_  = tid >> 6;
        const float gmv = gm[lane], bmv = bm[lane];
        for (int rr = 0; rr < 16; ++rr) {
            const int j = wv_ * 16 + rr;
            float v  = Us[j * 68 + lane];
            float mu = wsum64(v) * (1.f / 64.f);
            float dd = v - mu;
            float var = wsum64(dd * dd) * (1.f / 64.f);
            float z = dd * rsqrtf(var + 1e-5f) * gmv + bmv;
            At[lane * 68 + j] = z;
        }
    }
    __syncthreads();

    // h = gelu(z @ W1 + bm1); out_row += h . w2bar
    float a2[4][4];
    #pragma unroll
    for (int i = 0; i < 4; ++i)
        #pragma unroll
        for (int k = 0; k < 4; ++k) a2[i][k] = 0.f;
    #pragma unroll 4
    for (int c = 0; c < ND; ++c) {
        float4 a = *(const float4*)&At[c * 68 + j0];
        float4 w = *(const float4*)(W1 + c * ND + d0);
        float av[4] = {a.x, a.y, a.z, a.w};
        float wv[4] = {w.x, w.y, w.z, w.w};
        #pragma unroll
        for (int i = 0; i < 4; ++i)
            #pragma unroll
            for (int k = 0; k < 4; ++k) a2[i][k] = fmaf(av[i], wv[k], a2[i][k]);
    }
    float part[4] = {0.f, 0.f, 0.f, 0.f};
    #pragma unroll
    for (int i = 0; i < 4; ++i) {
        #pragma unroll
        for (int k = 0; k < 4; ++k) {
            float h = a2[i][k] + bm1[d0 + k];
            float g = 0.5f * h * (1.f + erff(h * 0.70710678118654752f));
            part[i] = fmaf(g, w2b[d0 + k], part[i]);
        }
        part[i] = wsum16(part[i]);
    }
    if ((tid & 15) == 0) {
        #pragma unroll
        for (int i = 0; i < 4; ++i)
            out[(size_t)b * NHW + n0 + j0 + i] = part[i] + bm2b;
    }
}

extern "C" void kernel_launch(void* const* d_in, const int* in_sizes, int n_in,
                              void* d_out, int out_size, void* d_ws, size_t ws_size,
                              hipStream_t stream) {
    (void)in_sizes; (void)n_in; (void)out_size; (void)ws_size;
    const float* x    = (const float*)d_in[0];
    const float* We   = (const float*)d_in[1];
    const float* be   = (const float*)d_in[2];
    const float* g1   = (const float*)d_in[3];
    const float* b1   = (const float*)d_in[4];
    const float* g2   = (const float*)d_in[5];
    const float* b2   = (const float*)d_in[6];
    const float* Wqkv = (const float*)d_in[7];
    const float* bqkv = (const float*)d_in[8];
    const float* Wp   = (const float*)d_in[9];
    const float* bp   = (const float*)d_in[10];
    const float* gm   = (const float*)d_in[11];
    const float* bm   = (const float*)d_in[12];
    const float* W1   = (const float*)d_in[13];
    const float* bm1  = (const float*)d_in[14];
    const float* W2   = (const float*)d_in[15];
    const float* bm2  = (const float*)d_in[16];
    float* out = (float*)d_out;

    float* qb = (float*)d_ws;
    float* kb = qb + (size_t)NB * NHW * ND;
    float* vb = kb + (size_t)NB * NHW * ND;

    dim3 grid(NT, NB), blk(TB);
    k_embed_qkv<<<grid, blk, 0, stream>>>(x, We, be, g1, b1, g2, b2, Wqkv, bqkv, qb, kb, vb);
    k_attn<<<grid, blk, 0, stream>>>(qb, kb, vb, qb);
    k_post<<<grid, blk, 0, stream>>>(qb, Wp, bp, gm, bm, W1, bm1, W2, bm2, out);
}

// Round 3
// 518.086 us; speedup vs baseline: 3.1179x; 3.1179x over previous
//
#include <hip/hip_runtime.h>
#include <math.h>

#define TB 256
#define NB 32
#define NC 128
#define NHW 3136
#define ND 64
#define NT 49

typedef _Float16 half8 __attribute__((ext_vector_type(8)));
typedef __fp16 fp16x2 __attribute__((ext_vector_type(2)));
typedef float float4v __attribute__((ext_vector_type(4)));

__device__ __forceinline__ float wsum64(float v){
    v += __shfl_xor(v, 32);
    v += __shfl_xor(v, 16);
    v += __shfl_xor(v, 8);
    v += __shfl_xor(v, 4);
    v += __shfl_xor(v, 2);
    v += __shfl_xor(v, 1);
    return v;
}
__device__ __forceinline__ float wsum16(float v){
    v += __shfl_xor(v, 8);
    v += __shfl_xor(v, 4);
    v += __shfl_xor(v, 2);
    v += __shfl_xor(v, 1);
    return v;
}

__device__ __forceinline__ void pack4h(_Float16* dst, float v0, float v1, float v2, float v3){
    union { fp16x2 h[2]; uint2 u; } pk;
    pk.h[0] = __builtin_amdgcn_cvt_pkrtz(v0, v1);
    pk.h[1] = __builtin_amdgcn_cvt_pkrtz(v2, v3);
    *(uint2*)dst = pk.u;
}

// ---------------- Kernel 1: embed + LN1 + LN2 + QKV ----------------
// grid (49, 32), 256 threads. Outputs (f16): qh [B][N][64] (×0.125 folded),
// kh [B][N][64], vT [B][64][N] (transposed).
__global__ __launch_bounds__(TB) void k_embed_qkv(
    const float* __restrict__ x,    // [B][C][HW]
    const float* __restrict__ We,   // [C][D]
    const float* __restrict__ be,
    const float* __restrict__ g1, const float* __restrict__ b1,
    const float* __restrict__ g2, const float* __restrict__ b2,
    const float* __restrict__ Wqkv, // [D][3D]
    const float* __restrict__ bqkv,
    _Float16* __restrict__ qh, _Float16* __restrict__ khb, _Float16* __restrict__ vtb)
{
    __shared__ float ts[64 * 68];   // t[j][d], stride 68
    __shared__ float zt[64 * 68];   // z^T[c][j], stride 68

    const int b   = blockIdx.y;
    const int n0  = blockIdx.x * 64;
    const int tid = threadIdx.x;
    const int j0  = (tid >> 4) * 4;     // 4 token rows
    const int d0  = (tid & 15) * 4;     // 4 feature cols

    // ---- Phase A: t[j][d] = sum_c x[b][c][n0+j] * We[c][d] + be[d]
    float acc[4][4];
    #pragma unroll
    for (int i = 0; i < 4; ++i)
        #pragma unroll
        for (int k = 0; k < 4; ++k) acc[i][k] = 0.f;

    const float* xp = x + (size_t)b * NC * NHW + n0 + j0;
    #pragma unroll 4
    for (int c = 0; c < NC; ++c) {
        float4 a = *(const float4*)(xp + (size_t)c * NHW);
        float4 w = *(const float4*)(We + c * ND + d0);
        float av[4] = {a.x, a.y, a.z, a.w};
        float wv[4] = {w.x, w.y, w.z, w.w};
        #pragma unroll
        for (int i = 0; i < 4; ++i)
            #pragma unroll
            for (int k = 0; k < 4; ++k) acc[i][k] = fmaf(av[i], wv[k], acc[i][k]);
    }
    {
        float4 bev = *(const float4*)(be + d0);
        float bv[4] = {bev.x, bev.y, bev.z, bev.w};
        #pragma unroll
        for (int i = 0; i < 4; ++i) {
            float4 r;
            r.x = acc[i][0] + bv[0]; r.y = acc[i][1] + bv[1];
            r.z = acc[i][2] + bv[2]; r.w = acc[i][3] + bv[3];
            *(float4*)&ts[(j0 + i) * 68 + d0] = r;
        }
    }
    __syncthreads();

    // ---- Phase B: double LayerNorm per token row; write transposed z^T[c][j]
    {
        const int lane = tid & 63;
        const int wv_  = tid >> 6;
        const float g1v = g1[lane], b1v = b1[lane];
        const float g2v = g2[lane], b2v = b2[lane];
        for (int rr = 0; rr < 16; ++rr) {
            const int j = wv_ * 16 + rr;
            float v  = ts[j * 68 + lane];
            float mu = wsum64(v) * (1.f / 64.f);
            float dd = v - mu;
            float var = wsum64(dd * dd) * (1.f / 64.f);
            float y  = dd * rsqrtf(var + 1e-5f) * g1v + b1v;
            float mu2 = wsum64(y) * (1.f / 64.f);
            float d2  = y - mu2;
            float var2 = wsum64(d2 * d2) * (1.f / 64.f);
            float z = d2 * rsqrtf(var2 + 1e-5f) * g2v + b2v;
            zt[lane * 68 + j] = z;
        }
    }
    __syncthreads();

    // ---- Phase C: qkv[j][d3] = z[j][:] @ Wqkv + bqkv, emit f16
    #pragma unroll 1
    for (int blkd = 0; blkd < 3; ++blkd) {
        float a2[4][4];
        #pragma unroll
        for (int i = 0; i < 4; ++i)
            #pragma unroll
            for (int k = 0; k < 4; ++k) a2[i][k] = 0.f;
        #pragma unroll 4
        for (int c = 0; c < ND; ++c) {
            float4 a = *(const float4*)&zt[c * 68 + j0];
            float4 w = *(const float4*)(Wqkv + c * 192 + blkd * 64 + d0);
            float av[4] = {a.x, a.y, a.z, a.w};
            float wv[4] = {w.x, w.y, w.z, w.w};
            #pragma unroll
            for (int i = 0; i < 4; ++i)
                #pragma unroll
                for (int k = 0; k < 4; ++k) a2[i][k] = fmaf(av[i], wv[k], a2[i][k]);
        }
        float4 bq = *(const float4*)(bqkv + blkd * 64 + d0);
        float bv[4] = {bq.x, bq.y, bq.z, bq.w};
        if (blkd < 2) {
            const float scale = (blkd == 0) ? 0.125f : 1.0f;
            _Float16* obuf = (blkd == 0) ? qh : khb;
            #pragma unroll
            for (int i = 0; i < 4; ++i) {
                pack4h(obuf + ((size_t)(b * NHW + n0 + j0 + i)) * ND + d0,
                       (a2[i][0] + bv[0]) * scale, (a2[i][1] + bv[1]) * scale,
                       (a2[i][2] + bv[2]) * scale, (a2[i][3] + bv[3]) * scale);
            }
        } else {
            #pragma unroll
            for (int k = 0; k < 4; ++k) {
                pack4h(vtb + ((size_t)(b * ND + d0 + k)) * NHW + n0 + j0,
                       a2[0][k] + bv[k], a2[1][k] + bv[k],
                       a2[2][k] + bv[k], a2[3][k] + bv[k]);
            }
        }
    }
}

// ---------------- Kernel 2: MFMA flash attention ----------------
// grid (25, 32), 256 threads = 4 waves. Block: 128 Q rows; wave: 32 Q rows.
// S^T = K @ Q^T  (A=K m=key, B=Q n=qrow) -> softmax in-lane ->
// P to LDS -> O = P @ V (A=P m=qrow, B=V n=d, from vT).
__global__ __launch_bounds__(TB) void k_attn(
    const _Float16* __restrict__ qh, const _Float16* __restrict__ khb,
    const _Float16* __restrict__ vtb, float* __restrict__ ob)
{
    __shared__ _Float16 Ksh[64 * 72];        // K[key][d], pad 72
    __shared__ _Float16 Vsh[64 * 72];        // V^T[d][key], pad 72
    __shared__ _Float16 Psh[4 * 32 * 72];    // per-wave P[qrow][key], pad 72

    const int b    = blockIdx.y;
    const int n0   = blockIdx.x * 128;
    const int tid  = threadIdx.x;
    const int w    = tid >> 6;
    const int lane = tid & 63;
    const int quad = lane >> 4;
    const int c    = lane & 15;

    // Q fragments (B-operand): n=qrow=lane&15, k=d=quad*8+j
    half8 qf[2][2];
    #pragma unroll
    for (int qt = 0; qt < 2; ++qt) {
        int row = n0 + w * 32 + qt * 16 + c;
        row = row < NHW ? row : NHW - 1;
        const _Float16* qp = qh + ((size_t)(b * NHW + row)) * ND + quad * 8;
        qf[qt][0] = *(const half8*)(qp);
        qf[qt][1] = *(const half8*)(qp + 32);
    }

    float4v o[2][4];
    #pragma unroll
    for (int qt = 0; qt < 2; ++qt)
        #pragma unroll
        for (int nt = 0; nt < 4; ++nt) o[qt][nt] = (float4v){0.f, 0.f, 0.f, 0.f};
    float m[2] = {-1e30f, -1e30f}, l[2] = {0.f, 0.f};

    const _Float16* kbase = khb + ((size_t)b * NHW) * ND;
    const _Float16* vbase = vtb + ((size_t)b * ND) * NHW;
    _Float16* Pw = Psh + w * (32 * 72);

    for (int kt = 0; kt < NT; ++kt) {
        __syncthreads();
        // stage K tile [64 keys][64 d] and V^T tile [64 d][64 keys] (pure f16 copy)
        #pragma unroll
        for (int i = 0; i < 2; ++i) {
            int ch = tid + 256 * i;          // 512 chunks of 16B per array
            int row = ch >> 3, off = (ch & 7) * 8;
            *(uint4*)&Ksh[row * 72 + off] =
                *(const uint4*)(kbase + ((size_t)(kt * 64 + row)) * ND + off);
            *(uint4*)&Vsh[row * 72 + off] =
                *(const uint4*)(vbase + (size_t)row * NHW + kt * 64 + off);
        }
        __syncthreads();

        // K A-fragments: m=key=lane&15 (+16*mt), k=d=quad*8+j (+32*kc)
        half8 ka[4][2];
        #pragma unroll
        for (int mt = 0; mt < 4; ++mt) {
            const _Float16* kp = &Ksh[(mt * 16 + c) * 72 + quad * 8];
            ka[mt][0] = *(const half8*)(kp);
            ka[mt][1] = *(const half8*)(kp + 32);
        }

        // S^T = K @ Q^T : C col=qrow=lane&15, row=key=quad*4+reg (+16*mt)
        float4v s[2][4];
        #pragma unroll
        for (int qt = 0; qt < 2; ++qt)
            #pragma unroll
            for (int mt = 0; mt < 4; ++mt) {
                float4v z = (float4v){0.f, 0.f, 0.f, 0.f};
                z = __builtin_amdgcn_mfma_f32_16x16x32_f16(ka[mt][0], qf[qt][0], z, 0, 0, 0);
                z = __builtin_amdgcn_mfma_f32_16x16x32_f16(ka[mt][1], qf[qt][1], z, 0, 0, 0);
                s[qt][mt] = z;
            }

        // online softmax, entirely per-lane rows (qrow = qt*16 + c)
        #pragma unroll
        for (int qt = 0; qt < 2; ++qt) {
            float rm = -1e30f;
            #pragma unroll
            for (int mt = 0; mt < 4; ++mt)
                #pragma unroll
                for (int r = 0; r < 4; ++r) rm = fmaxf(rm, s[qt][mt][r]);
            rm = fmaxf(rm, __shfl_xor(rm, 16));
            rm = fmaxf(rm, __shfl_xor(rm, 32));
            float mn = fmaxf(m[qt], rm);
            float rs = 0.f;
            #pragma unroll
            for (int mt = 0; mt < 4; ++mt)
                #pragma unroll
                for (int r = 0; r < 4; ++r) {
                    float p = __expf(s[qt][mt][r] - mn);
                    s[qt][mt][r] = p;
                    rs += p;
                }
            rs += __shfl_xor(rs, 16);
            rs += __shfl_xor(rs, 32);
            float al = __expf(m[qt] - mn);
            l[qt] = l[qt] * al + rs;
            m[qt] = mn;
            // broadcast alpha to O layout rows (row = quad*4 + reg)
            float aO[4];
            #pragma unroll
            for (int r = 0; r < 4; ++r) aO[r] = __shfl(al, quad * 4 + r);
            #pragma unroll
            for (int nt = 0; nt < 4; ++nt)
                #pragma unroll
                for (int r = 0; r < 4; ++r) o[qt][nt][r] *= aO[r];
        }

        // write P (f16) : lane holds rows qrow=qt*16+c, keys mt*16+quad*4+reg(0..3 contiguous)
        #pragma unroll
        for (int qt = 0; qt < 2; ++qt)
            #pragma unroll
            for (int mt = 0; mt < 4; ++mt)
                pack4h(&Pw[(qt * 16 + c) * 72 + mt * 16 + quad * 4],
                       s[qt][mt][0], s[qt][mt][1], s[qt][mt][2], s[qt][mt][3]);

        // P A-fragments: m=qrow=lane&15 (+16*qt), k=key=quad*8+j (+32*kc)
        half8 pa[2][2];
        #pragma unroll
        for (int qt = 0; qt < 2; ++qt) {
            const _Float16* pp = &Pw[(qt * 16 + c) * 72 + quad * 8];
            pa[qt][0] = *(const half8*)(pp);
            pa[qt][1] = *(const half8*)(pp + 32);
        }

        // O += P @ V : B=V k=key, n=d -> from Vsh[d][key]
        #pragma unroll
        for (int nt = 0; nt < 4; ++nt) {
            const _Float16* vp = &Vsh[(nt * 16 + c) * 72 + quad * 8];
            half8 vf0 = *(const half8*)(vp);
            half8 vf1 = *(const half8*)(vp + 32);
            #pragma unroll
            for (int qt = 0; qt < 2; ++qt) {
                o[qt][nt] = __builtin_amdgcn_mfma_f32_16x16x32_f16(pa[qt][0], vf0, o[qt][nt], 0, 0, 0);
                o[qt][nt] = __builtin_amdgcn_mfma_f32_16x16x32_f16(pa[qt][1], vf1, o[qt][nt], 0, 0, 0);
            }
        }
    }

    // epilogue: normalize by l (redistribute to O layout) and store fp32
    #pragma unroll
    for (int qt = 0; qt < 2; ++qt) {
        #pragma unroll
        for (int r = 0; r < 4; ++r) {
            float li = __shfl(l[qt], quad * 4 + r);
            float inv = 1.f / li;
            int row = n0 + w * 32 + qt * 16 + quad * 4 + r;
            if (row < NHW) {
                float* op = ob + ((size_t)(b * NHW + row)) * ND + c;
                #pragma unroll
                for (int nt = 0; nt < 4; ++nt) op[nt * 16] = o[qt][nt][r] * inv;
            }
        }
    }
}

// ---------------- Kernel 3: proj + LN + MLP(gelu) + channel-mean ----------------
__global__ __launch_bounds__(TB) void k_post(
    const float* __restrict__ ain,  // attention output [B][N][64]
    const float* __restrict__ Wp, const float* __restrict__ bp,
    const float* __restrict__ gm, const float* __restrict__ bm,
    const float* __restrict__ W1, const float* __restrict__ bm1,
    const float* __restrict__ W2, const float* __restrict__ bm2,
    float* __restrict__ out)
{
    __shared__ float At[64 * 68];   // A^T[c][j], reused as z2^T[c][j]
    __shared__ float Us[64 * 68];   // u[j][d]
    __shared__ float w2b[64];
    __shared__ float bm2b;

    const int b   = blockIdx.y;
    const int n0  = blockIdx.x * 64;
    const int tid = threadIdx.x;
    const int j0  = (tid >> 4) * 4;
    const int d0  = (tid & 15) * 4;

    if (tid < 64) {
        float s = 0.f;
        for (int d = 0; d < 64; ++d) s += W2[tid * 64 + d];
        w2b[tid] = s * (1.f / 64.f);
    }
    if (tid == 64) {
        float s = 0.f;
        for (int d = 0; d < 64; ++d) s += bm2[d];
        bm2b = s * (1.f / 64.f);
    }
    #pragma unroll
    for (int i = 0; i < 4; ++i) {
        int f4i = tid + 256 * i;
        int r = f4i >> 4, c4 = f4i & 15;
        float4 av = *(const float4*)(ain + ((size_t)(b * NHW + n0 + r)) * ND + c4 * 4);
        At[(c4 * 4 + 0) * 68 + r] = av.x;
        At[(c4 * 4 + 1) * 68 + r] = av.y;
        At[(c4 * 4 + 2) * 68 + r] = av.z;
        At[(c4 * 4 + 3) * 68 + r] = av.w;
    }
    __syncthreads();

    // u = A @ Wp + bp
    float acc[4][4];
    #pragma unroll
    for (int i = 0; i < 4; ++i)
        #pragma unroll
        for (int k = 0; k < 4; ++k) acc[i][k] = 0.f;
    #pragma unroll 4
    for (int c = 0; c < ND; ++c) {
        float4 a = *(const float4*)&At[c * 68 + j0];
        float4 w = *(const float4*)(Wp + c * ND + d0);
        float av[4] = {a.x, a.y, a.z, a.w};
        float wv[4] = {w.x, w.y, w.z, w.w};
        #pragma unroll
        for (int i = 0; i < 4; ++i)
            #pragma unroll
            for (int k = 0; k < 4; ++k) acc[i][k] = fmaf(av[i], wv[k], acc[i][k]);
    }
    {
        float4 bpv = *(const float4*)(bp + d0);
        float bv[4] = {bpv.x, bpv.y, bpv.z, bpv.w};
        #pragma unroll
        for (int i = 0; i < 4; ++i) {
            float4 r;
            r.x = acc[i][0] + bv[0]; r.y = acc[i][1] + bv[1];
            r.z = acc[i][2] + bv[2]; r.w = acc[i][3] + bv[3];
            *(float4*)&Us[(j0 + i) * 68 + d0] = r;
        }
    }
    __syncthreads();

    // LN (gm, bm); write z^T into At
    {
        const int lane = tid & 63;
        const int wv_  = tid >> 6;
        const float gmv = gm[lane], bmv = bm[lane];
        for (int rr = 0; rr < 16; ++rr) {
            const int j = wv_ * 16 + rr;
            float v  = Us[j * 68 + lane];
            float mu = wsum64(v) * (1.f / 64.f);
            float dd = v - mu;
            float var = wsum64(dd * dd) * (1.f / 64.f);
            float z = dd * rsqrtf(var + 1e-5f) * gmv + bmv;
            At[lane * 68 + j] = z;
        }
    }
    __syncthreads();

    // h = gelu(z @ W1 + bm1); out_row += h . w2bar
    float a2[4][4];
    #pragma unroll
    for (int i = 0; i < 4; ++i)
        #pragma unroll
        for (int k = 0; k < 4; ++k) a2[i][k] = 0.f;
    #pragma unroll 4
    for (int c = 0; c < ND; ++c) {
        float4 a = *(const float4*)&At[c * 68 + j0];
        float4 w = *(const float4*)(W1 + c * ND + d0);
        float av[4] = {a.x, a.y, a.z, a.w};
        float wv[4] = {w.x, w.y, w.z, w.w};
        #pragma unroll
        for (int i = 0; i < 4; ++i)
            #pragma unroll
            for (int k = 0; k < 4; ++k) a2[i][k] = fmaf(av[i], wv[k], a2[i][k]);
    }
    float part[4] = {0.f, 0.f, 0.f, 0.f};
    #pragma unroll
    for (int i = 0; i < 4; ++i) {
        #pragma unroll
        for (int k = 0; k < 4; ++k) {
            float h = a2[i][k] + bm1[d0 + k];
            float g = 0.5f * h * (1.f + erff(h * 0.70710678118654752f));
            part[i] = fmaf(g, w2b[d0 + k], part[i]);
        }
        part[i] = wsum16(part[i]);
    }
    if ((tid & 15) == 0) {
        #pragma unroll
        for (int i = 0; i < 4; ++i)
            out[(size_t)b * NHW + n0 + j0 + i] = part[i] + bm2b;
    }
}

extern "C" void kernel_launch(void* const* d_in, const int* in_sizes, int n_in,
                              void* d_out, int out_size, void* d_ws, size_t ws_size,
                              hipStream_t stream) {
    (void)in_sizes; (void)n_in; (void)out_size; (void)ws_size;
    const float* x    = (const float*)d_in[0];
    const float* We   = (const float*)d_in[1];
    const float* be   = (const float*)d_in[2];
    const float* g1   = (const float*)d_in[3];
    const float* b1   = (const float*)d_in[4];
    const float* g2   = (const float*)d_in[5];
    const float* b2   = (const float*)d_in[6];
    const float* Wqkv = (const float*)d_in[7];
    const float* bqkv = (const float*)d_in[8];
    const float* Wp   = (const float*)d_in[9];
    const float* bp   = (const float*)d_in[10];
    const float* gm   = (const float*)d_in[11];
    const float* bm   = (const float*)d_in[12];
    const float* W1   = (const float*)d_in[13];
    const float* bm1  = (const float*)d_in[14];
    const float* W2   = (const float*)d_in[15];
    const float* bm2  = (const float*)d_in[16];
    float* out = (float*)d_out;

    _Float16* qh  = (_Float16*)d_ws;
    _Float16* khb = qh  + (size_t)NB * NHW * ND;
    _Float16* vtb = khb + (size_t)NB * NHW * ND;
    float*    obf = (float*)(vtb + (size_t)NB * NHW * ND);

    dim3 blk(TB);
    dim3 ge(NT, NB);
    dim3 ga(25, NB);
    k_embed_qkv<<<ge, blk, 0, stream>>>(x, We, be, g1, b1, g2, b2, Wqkv, bqkv, qh, khb, vtb);
    k_attn<<<ga, blk, 0, stream>>>(qh, khb, vtb, obf);
    k_post<<<ge, blk, 0, stream>>>(obf, Wp, bp, gm, bm, W1, bm1, W2, bm2, out);
}